// Round 3
// baseline (187.742 us; speedup 1.0000x reference)
//
#include <hip/hip_runtime.h>
#include <hip/hip_bf16.h>
#include <math.h>

#define S_LEN 2048
#define DIM   128
#define NHEAD 16
#define BQ    62          // conv-output rows per workgroup
#define BK    64          // k-tile width
#define SCALE 0.08838834764831845f  // 1/sqrt(128)

typedef __attribute__((ext_vector_type(8))) short bf16x8;
typedef __attribute__((ext_vector_type(4))) float f32x4;

__device__ inline short f2bf(float f) {
  union { float f; unsigned u; } v; v.f = f;
  unsigned r = v.u + 0x7fffu + ((v.u >> 16) & 1u);
  return (short)(r >> 16);
}

// One workgroup = one (head, q-tile). Raw score tile rows [q0-2, q0+62) (64 rows),
// conv output rows [q0, q0+62). Lag pipeline: raw tile t computed (Phase B), then
// conv/softmax/PV for tile t-1 (Phase C). Right halo = col 0 of tile t (rawS other
// buffer); left halo = col 63 of tile t-2 (haloL, double-buffered); final tile's
// right halo is provably zero (scores above diagonal are 0 pre-conv).
// Phase C: lane (lm,lg) owns row wid*16+lm, cols {lg*8..+7}U{32+lg*8..+7} == the
// PV A-fragment footprint. Softmax reduce = 2 shfl_xor hops; m/l state per-lane;
// P never touches LDS. 3 barriers per iteration.
__global__ __launch_bounds__(256, 2)
void convattn_kernel(const float* __restrict__ Q, const float* __restrict__ K,
                     const float* __restrict__ V, const float* __restrict__ W,
                     float* __restrict__ Out) {
  __shared__ __align__(16) short Kt[64][136];      // K tile bf16 [kv][d], 272B rows (aligned, balanced)
  __shared__ __align__(16) short Vt[128][72];      // V^T tile bf16 [d][kv], 144B rows (aligned, balanced)
  __shared__ __align__(16) float rawS[2][64][67];  // raw scores fp32, dbl-buffered, odd dword stride
  __shared__ float haloL[2][64];                   // col k0-1 per row, dbl-buffered

  const int h  = blockIdx.y;
  const int qt = (gridDim.x - 1) - blockIdx.x;     // longest-first scheduling
  const int q0 = qt * BQ;
  const int qr0 = q0 - 2;
  const int q_cap = min(q0 + BQ - 1, S_LEN - 1);
  const int T = q_cap / BK + 1;

  const int tid  = threadIdx.x;
  const int wid  = tid >> 6;
  const int lane = tid & 63;
  const int lm   = lane & 15;   // MFMA m/n index
  const int lg   = lane >> 4;   // MFMA k-group

  const float* Qh = Q + (size_t)h * S_LEN * DIM;
  const float* Kh = K + (size_t)h * S_LEN * DIM;
  const float* Vh = V + (size_t)h * S_LEN * DIM;
  float* Oh = Out + (size_t)h * S_LEN * DIM;

  float wk[9];
  #pragma unroll
  for (int i = 0; i < 9; ++i) wk[i] = W[h * 9 + i];

  // ---- Q fragments (A operand), hoisted ----
  bf16x8 qf[4];
  {
    int qrow = qr0 + wid * 16 + lm;
    int qc = qrow < 0 ? 0 : (qrow >= S_LEN ? S_LEN - 1 : qrow);
    const float* qp = Qh + (size_t)qc * DIM;
    #pragma unroll
    for (int kk = 0; kk < 4; ++kk) {
      int d0 = kk * 32 + lg * 8;
      float4 a = *(const float4*)(qp + d0);
      float4 b = *(const float4*)(qp + d0 + 4);
      bf16x8 f;
      f[0]=f2bf(a.x); f[1]=f2bf(a.y); f[2]=f2bf(a.z); f[3]=f2bf(a.w);
      f[4]=f2bf(b.x); f[5]=f2bf(b.y); f[6]=f2bf(b.z); f[7]=f2bf(b.w);
      qf[kk] = f;
    }
  }

  if (tid < 64) haloL[0][tid] = 0.f;

  // per-lane online-softmax state for row wid*16+lm (replicated across lg)
  float m_state = -INFINITY, l_state = 0.f;

  f32x4 oacc[8];
  const f32x4 zero4 = {0.f, 0.f, 0.f, 0.f};
  #pragma unroll
  for (int cb = 0; cb < 8; ++cb) oacc[cb] = zero4;

  for (int t = 0; t <= T; ++t) {
    __syncthreads();  // protect Kt/Vt reuse from previous iteration's reads
    // ---- Phase A: stage K tile t (vectorized b128 writes), V tile t-1 (transposed) ----
    if (t < T) {
      int k0 = t * BK;
      int r = tid >> 2, dc = (tid & 3) * 32;
      const float* kp = Kh + (size_t)(k0 + r) * DIM + dc;
      #pragma unroll
      for (int j8 = 0; j8 < 4; ++j8) {
        float4 a = *(const float4*)(kp + j8 * 8);
        float4 b = *(const float4*)(kp + j8 * 8 + 4);
        bf16x8 f;
        f[0]=f2bf(a.x); f[1]=f2bf(a.y); f[2]=f2bf(a.z); f[3]=f2bf(a.w);
        f[4]=f2bf(b.x); f[5]=f2bf(b.y); f[6]=f2bf(b.z); f[7]=f2bf(b.w);
        *(bf16x8*)&Kt[r][dc + j8 * 8] = f;
      }
    }
    if (t > 0) {
      int kv0 = (t - 1) * BK;
      int r = tid >> 2, dc = (tid & 3) * 32;
      const float* vp = Vh + (size_t)(kv0 + r) * DIM + dc;
      #pragma unroll
      for (int j = 0; j < 32; j += 4) {
        float4 v = *(const float4*)(vp + j);
        Vt[dc + j][r]     = f2bf(v.x);
        Vt[dc + j + 1][r] = f2bf(v.y);
        Vt[dc + j + 2][r] = f2bf(v.z);
        Vt[dc + j + 3][r] = f2bf(v.w);
      }
    }
    __syncthreads();
    // ---- Phase B: QK^T MFMA -> masked raw tile t ----
    if (t < T) {
      int k0 = t * BK;
      f32x4 sacc[4];
      #pragma unroll
      for (int cb = 0; cb < 4; ++cb) sacc[cb] = zero4;
      #pragma unroll
      for (int kk = 0; kk < 4; ++kk) {
        #pragma unroll
        for (int cb = 0; cb < 4; ++cb) {
          bf16x8 bf = *(const bf16x8*)&Kt[cb * 16 + lm][kk * 32 + lg * 8];
          sacc[cb] = __builtin_amdgcn_mfma_f32_16x16x32_bf16(qf[kk], bf, sacc[cb], 0, 0, 0);
        }
      }
      const int buf = t & 1;
      #pragma unroll
      for (int cb = 0; cb < 4; ++cb) {
        #pragma unroll
        for (int i = 0; i < 4; ++i) {
          int rr = wid * 16 + lg * 4 + i;       // C/D: row = 4*(l>>4)+i
          int cc = cb * 16 + lm;                //      col = l&15
          rawS[buf][rr][cc] = ((k0 + cc) <= (qr0 + rr)) ? sacc[cb][i] * SCALE : 0.f;
        }
      }
    }
    __syncthreads();
    // ---- Phase C: conv + online softmax -> A-frags in regs -> rescale + PV ----
    if (t > 0) {
      const int tp = t - 1;
      const int pb = tp & 1, nb = pb ^ 1;
      const int hb = tp & 1, hn = hb ^ 1;
      const int c0p = tp * BK;
      const bool haveRight = (t < T);
      const int r = wid * 16 + lm;
      const int q = qr0 + r;
      const bool rowvalid = (r >= 2) && (q <= q_cap);
      const int r2 = max(r - 2, 0), r1 = max(r - 1, 0);

      float sv[16];
      float pm = -INFINITY;
      #pragma unroll
      for (int ch = 0; ch < 2; ++ch) {
        const int cs = ch * 32 + lg * 8;
        float l0, l1, l2, m0, m1, m2;
        if (cs == 0) { l0 = haloL[hb][r2]; l1 = haloL[hb][r1]; l2 = haloL[hb][r]; }
        else { l0 = rawS[pb][r2][cs - 1]; l1 = rawS[pb][r1][cs - 1]; l2 = rawS[pb][r][cs - 1]; }
        m0 = rawS[pb][r2][cs]; m1 = rawS[pb][r1][cs]; m2 = rawS[pb][r][cs];
        #pragma unroll
        for (int c = 0; c < 8; ++c) {
          float n0, n1, n2;
          const int nc = cs + c + 1;
          if (nc < 64) {
            n0 = rawS[pb][r2][nc]; n1 = rawS[pb][r1][nc]; n2 = rawS[pb][r][nc];
          } else if (haveRight) {
            n0 = rawS[nb][r2][0]; n1 = rawS[nb][r1][0]; n2 = rawS[nb][r][0];
          } else {
            n0 = 0.f; n1 = 0.f; n2 = 0.f;
          }
          float cv = wk[0]*l0 + wk[1]*m0 + wk[2]*n0
                   + wk[3]*l1 + wk[4]*m1 + wk[5]*n1
                   + wk[6]*l2 + wk[7]*m2 + wk[8]*n2;
          bool vld = rowvalid && ((c0p + cs + c) <= q);
          sv[ch * 8 + c] = vld ? cv : -INFINITY;
          pm = fmaxf(pm, sv[ch * 8 + c]);
          l0 = m0; m0 = n0; l1 = m1; m1 = n1; l2 = m2; m2 = n2;
        }
      }
      // row reduce across the 4 lg-lanes (lanes lm, lm+16, lm+32, lm+48)
      pm = fmaxf(pm, __shfl_xor(pm, 16));
      pm = fmaxf(pm, __shfl_xor(pm, 32));
      const float mn = fmaxf(m_state, pm);
      const float al = __expf(m_state - mn);
      float ps = 0.f;
      short pf16[16];
      #pragma unroll
      for (int c = 0; c < 16; ++c) {
        float p = __expf(sv[c] - mn);
        ps += p;
        pf16[c] = f2bf(p);
      }
      ps += __shfl_xor(ps, 16);
      ps += __shfl_xor(ps, 32);
      m_state = mn;
      l_state = al * l_state + ps;
      if (lg == 0) haloL[hn][r] = rawS[pb][r][63];   // left halo for next tile
      // ---- rescale oacc by alpha of its rows ----
      #pragma unroll
      for (int i = 0; i < 4; ++i) {
        float a = __shfl(al, lg * 4 + i);            // lane lg*4+i holds row wid*16+lg*4+i
        #pragma unroll
        for (int cb = 0; cb < 8; ++cb) oacc[cb][i] *= a;
      }
      // ---- PV MFMA: A-frags straight from registers ----
      bf16x8 pf0, pf1;
      #pragma unroll
      for (int c = 0; c < 8; ++c) { pf0[c] = pf16[c]; pf1[c] = pf16[8 + c]; }
      #pragma unroll
      for (int kk = 0; kk < 2; ++kk) {
        bf16x8 pf = kk ? pf1 : pf0;
        #pragma unroll
        for (int cb = 0; cb < 8; ++cb) {
          bf16x8 vf = *(const bf16x8*)&Vt[cb * 16 + lm][kk * 32 + lg * 8];
          oacc[cb] = __builtin_amdgcn_mfma_f32_16x16x32_bf16(pf, vf, oacc[cb], 0, 0, 0);
        }
      }
    }
  }

  // ---- epilogue: normalize and store ----
  #pragma unroll
  for (int i = 0; i < 4; ++i) {
    int rr = wid * 16 + lg * 4 + i;
    int q = qr0 + rr;
    float lr = __shfl(l_state, lg * 4 + i);
    if (rr >= 2 && q <= q_cap) {
      float inv = 1.f / lr;
      #pragma unroll
      for (int cb = 0; cb < 8; ++cb) {
        Oh[(size_t)q * DIM + cb * 16 + lm] = oacc[cb][i] * inv;
      }
    }
  }
}

extern "C" void kernel_launch(void* const* d_in, const int* in_sizes, int n_in,
                              void* d_out, int out_size, void* d_ws, size_t ws_size,
                              hipStream_t stream) {
  const float* Q = (const float*)d_in[0];
  const float* K = (const float*)d_in[1];
  const float* V = (const float*)d_in[2];
  const float* W = (const float*)d_in[3];
  float* Out = (float*)d_out;
  const int NQT = (S_LEN + BQ - 1) / BQ;   // 34
  dim3 grid(NQT, NHEAD);
  convattn_kernel<<<grid, 256, 0, stream>>>(Q, K, V, W, Out);
}

// Round 4
// 143.866 us; speedup vs baseline: 1.3050x; 1.3050x over previous
//
#include <hip/hip_runtime.h>
#include <hip/hip_bf16.h>
#include <math.h>

#define S_LEN 2048
#define DIM   128
#define NHEAD 16
#define BQ    62
#define BK    64
#define SCALE 0.08838834764831845f

typedef __attribute__((ext_vector_type(8))) short bf16x8;
typedef __attribute__((ext_vector_type(4))) float f32x4;

__device__ __forceinline__ short f2bf(float f) {
  union { float f; unsigned u; } v; v.f = f;
  unsigned r = v.u + 0x7fffu + ((v.u >> 16) & 1u);
  return (short)(r >> 16);
}
__device__ __forceinline__ float bhi(unsigned u) {
  union { unsigned v; float f; } x; x.v = u & 0xffff0000u; return x.f;
}
__device__ __forceinline__ float blo(unsigned u) {
  union { unsigned v; float f; } x; x.v = u << 16; return x.f;
}
__device__ __forceinline__ float b2f(short s) {
  union { unsigned v; float f; } x; x.v = ((unsigned)(unsigned short)s) << 16; return x.f;
}
__device__ __forceinline__ void gll16(const void* gsrc, void* ldst) {
  __builtin_amdgcn_global_load_lds(
      (const __attribute__((address_space(1))) void*)gsrc,
      (__attribute__((address_space(3))) void*)ldst, 16, 0, 0);
}

// ---------- pre-pass 1: K fp32 -> bf16*scale, 16B-chunk XOR-swizzled ----------
__global__ __launch_bounds__(256)
void prep_k(const float* __restrict__ K, short* __restrict__ Kb) {
  int gid = blockIdx.x * 256 + threadIdx.x;      // 16*2048*16 chunk-tasks
  int chunk = gid & 15;
  int row = gid >> 4;                            // h*2048 + k
  int k = row & (S_LEN - 1);
  const float* src = K + (size_t)row * DIM + chunk * 8;
  float4 a = *(const float4*)(src);
  float4 b = *(const float4*)(src + 4);
  bf16x8 o;
  o[0]=f2bf(a.x*SCALE); o[1]=f2bf(a.y*SCALE); o[2]=f2bf(a.z*SCALE); o[3]=f2bf(a.w*SCALE);
  o[4]=f2bf(b.x*SCALE); o[5]=f2bf(b.y*SCALE); o[6]=f2bf(b.z*SCALE); o[7]=f2bf(b.w*SCALE);
  int cp = (chunk & 8) | ((chunk & 7) ^ (k & 7));
  *(bf16x8*)(Kb + (size_t)row * DIM + cp * 8) = o;
}

// ---------- pre-pass 2: V fp32 -> V^T bf16 tiles [h][tile][d][64], swizzled ----------
__global__ __launch_bounds__(256)
void prep_v(const float* __restrict__ V, short* __restrict__ Vw) {
  __shared__ __align__(16) short lv[128][72];    // [d][kv], padded
  int tile = blockIdx.x, h = blockIdx.y;
  const float* src = V + ((size_t)h * S_LEN + tile * 64) * DIM;
  int kr = threadIdx.x >> 2, dq = (threadIdx.x & 3) * 32;
  const float* sp = src + (size_t)kr * DIM + dq;
  #pragma unroll
  for (int j = 0; j < 32; j += 4) {
    float4 v = *(const float4*)(sp + j);
    lv[dq + j][kr]     = f2bf(v.x);
    lv[dq + j + 1][kr] = f2bf(v.y);
    lv[dq + j + 2][kr] = f2bf(v.z);
    lv[dq + j + 3][kr] = f2bf(v.w);
  }
  __syncthreads();
  int d = threadIdx.x >> 1, cbase = (threadIdx.x & 1) * 4;
  short* dst = Vw + ((size_t)h * 32 + tile) * 8192 + (size_t)d * 64;
  #pragma unroll
  for (int c0 = 0; c0 < 4; ++c0) {
    int c = cbase + c0;
    bf16x8 val = *(const bf16x8*)&lv[d][c * 8];
    *(bf16x8*)(dst + ((c ^ (d & 7)) * 8)) = val;
  }
}

// ---------- main fused kernel ----------
// Lag pipeline per (head, q-tile): Phase B computes raw tile t (QK^T, masked, bf16
// in LDS), Phase C finishes tile t-1 (3x3 conv, online softmax, PV). K tiles
// double-buffered via global_load_lds with counted vmcnt (prefetch spans the whole
// iteration); V^T tile loads hide under Phase B. Raw barriers; 8 loads/wave/iter
// always (dummies at edges) so vmcnt(8)/vmcnt(4) are exact.
__global__ __launch_bounds__(256)
void convattn_main(const float* __restrict__ Q, const short* __restrict__ Kb,
                   const short* __restrict__ Vw, const float* __restrict__ W,
                   float* __restrict__ Out) {
  __shared__ __align__(16) short Kt2[2][64][128];   // 32 KB, linear (swizzle in data)
  __shared__ __align__(16) short Vt[128][64];       // 16 KB, linear (swizzle in data)
  __shared__ __align__(16) short rawS16[2][64][66]; // 16.9 KB, bf16 scores (2 pad cols)
  __shared__ short haloL16[2][64];

  const int h  = blockIdx.y;
  const int qt = (gridDim.x - 1) - blockIdx.x;      // longest-first
  const int q0 = qt * BQ;
  const int qr0 = q0 - 2;
  const int q_cap = min(q0 + BQ - 1, S_LEN - 1);
  const int T = q_cap / BK + 1;

  const int tid  = threadIdx.x;
  const int wid  = tid >> 6;
  const int lane = tid & 63;
  const int lm   = lane & 15;
  const int lg   = lane >> 4;

  const float* Qh = Q + (size_t)h * S_LEN * DIM;
  const short* KbH = Kb + (size_t)h * S_LEN * DIM;
  const short* VwH = Vw + (size_t)h * 32 * 8192;
  float* Oh = Out + (size_t)h * S_LEN * DIM;

  float wk[9];
  #pragma unroll
  for (int i = 0; i < 9; ++i) wk[i] = W[h * 9 + i];

  // Q fragments (bf16), hoisted
  bf16x8 qf[4];
  {
    int qrow = qr0 + wid * 16 + lm;
    int qc = qrow < 0 ? 0 : (qrow >= S_LEN ? S_LEN - 1 : qrow);
    const float* qp = Qh + (size_t)qc * DIM;
    #pragma unroll
    for (int kk = 0; kk < 4; ++kk) {
      int d0 = kk * 32 + lg * 8;
      float4 a = *(const float4*)(qp + d0);
      float4 b = *(const float4*)(qp + d0 + 4);
      bf16x8 f;
      f[0]=f2bf(a.x); f[1]=f2bf(a.y); f[2]=f2bf(a.z); f[3]=f2bf(a.w);
      f[4]=f2bf(b.x); f[5]=f2bf(b.y); f[6]=f2bf(b.z); f[7]=f2bf(b.w);
      qf[kk] = f;
    }
  }
  if (tid < 64) haloL16[0][tid] = 0;

  float m_state = -INFINITY, l_state = 0.f;
  f32x4 oacc[8];
  const f32x4 zero4 = {0.f, 0.f, 0.f, 0.f};
  #pragma unroll
  for (int cb = 0; cb < 8; ++cb) oacc[cb] = zero4;

  // drain Q/W loads so our vmcnt counts are exact, then prologue staging
  __builtin_amdgcn_sched_barrier(0);
  asm volatile("s_waitcnt vmcnt(0)" ::: "memory");
  {
    const char* vg = (const char*)VwH;                    // dummy V (tile 0)
    const char* kg = (const char*)KbH;                    // K tile 0
    char* vl = (char*)&Vt[0][0];
    char* kl = (char*)&Kt2[0][0][0];
    #pragma unroll
    for (int i = 0; i < 4; ++i) {
      int off = wid * 4096 + i * 1024;
      gll16(vg + off + lane * 16, vl + off);
    }
    #pragma unroll
    for (int i = 0; i < 4; ++i) {
      int off = wid * 4096 + i * 1024;
      gll16(kg + off + lane * 16, kl + off);
    }
  }

  for (int t = 0; t <= T; ++t) {
    // ---- B1: everyone done with previous Phase C (Vt reads, rawS reads) ----
    asm volatile("s_waitcnt lgkmcnt(0)" ::: "memory");
    __builtin_amdgcn_sched_barrier(0);
    __builtin_amdgcn_s_barrier();
    // issue V[t-1] then K[t+1]  (order matters for vmcnt counting)
    {
      int vsrc = t > 0 ? t - 1 : 0;
      int ksrc = (t + 1 < T) ? t + 1 : T - 1;
      const char* vg = (const char*)(VwH + (size_t)vsrc * 8192);
      const char* kg = (const char*)(KbH + (size_t)ksrc * BK * DIM);
      char* vl = (char*)&Vt[0][0];
      char* kl = (char*)&Kt2[(t + 1) & 1][0][0];
      #pragma unroll
      for (int i = 0; i < 4; ++i) {
        int off = wid * 4096 + i * 1024;
        gll16(vg + off + lane * 16, vl + off);
      }
      #pragma unroll
      for (int i = 0; i < 4; ++i) {
        int off = wid * 4096 + i * 1024;
        gll16(kg + off + lane * 16, kl + off);
      }
    }
    // ---- B2: K[t] (issued last iteration) complete; V+K just issued stay in flight ----
    asm volatile("s_waitcnt vmcnt(8)" ::: "memory");
    __builtin_amdgcn_sched_barrier(0);
    __builtin_amdgcn_s_barrier();
    // ---- Phase B: QK^T -> masked bf16 raw tile t ----
    if (t < T) {
      const short(*Ktile)[128] = Kt2[t & 1];
      int k0 = t * BK;
      f32x4 sacc[4];
      #pragma unroll
      for (int cb = 0; cb < 4; ++cb) sacc[cb] = zero4;
      #pragma unroll
      for (int kk = 0; kk < 4; ++kk) {
        #pragma unroll
        for (int cb = 0; cb < 4; ++cb) {
          int c = kk * 4 + lg;
          int cp = (c & 8) | ((c & 7) ^ (lm & 7));
          bf16x8 bf = *(const bf16x8*)((const char*)&Ktile[cb * 16 + lm][0] + cp * 16);
          sacc[cb] = __builtin_amdgcn_mfma_f32_16x16x32_bf16(qf[kk], bf, sacc[cb], 0, 0, 0);
        }
      }
      const int buf = t & 1;
      #pragma unroll
      for (int cb = 0; cb < 4; ++cb) {
        #pragma unroll
        for (int i = 0; i < 4; ++i) {
          int rr = wid * 16 + lg * 4 + i;
          int cc = cb * 16 + lm;
          float v = ((k0 + cc) <= (qr0 + rr)) ? sacc[cb][i] : 0.f;
          rawS16[buf][rr][cc] = f2bf(v);
        }
      }
    }
    // ---- B3: rawS visible; V[t-1] complete; K[t+1] still in flight ----
    asm volatile("s_waitcnt vmcnt(4) lgkmcnt(0)" ::: "memory");
    __builtin_amdgcn_sched_barrier(0);
    __builtin_amdgcn_s_barrier();
    // ---- Phase C: conv + online softmax + PV for tile t-1 ----
    if (t > 0) {
      const int tp = t - 1;
      const int pb = tp & 1, nb = pb ^ 1;
      const int c0p = tp * BK;
      const bool haveRight = (t < T);
      const int r = wid * 16 + lm;
      const int q = qr0 + r;
      const bool rowvalid = (r >= 2) && (q <= q_cap);
      const int a0 = max(r - 2, 0), a1 = max(r - 1, 0);
      const short* rp0 = &rawS16[pb][a0][0];
      const short* rp1 = &rawS16[pb][a1][0];
      const short* rp2 = &rawS16[pb][r][0];
      float hL0 = b2f(haloL16[pb][a0]);
      float hL1 = b2f(haloL16[pb][a1]);
      float hL2 = b2f(haloL16[pb][r]);
      float rt0 = haveRight ? b2f(rawS16[nb][a0][0]) : 0.f;
      float rt1 = haveRight ? b2f(rawS16[nb][a1][0]) : 0.f;
      float rt2 = haveRight ? b2f(rawS16[nb][r][0]) : 0.f;

      float sv[16];
      float pm = -INFINITY;
      #pragma unroll
      for (int ch = 0; ch < 2; ++ch) {
        const int cs = ch * 32 + lg * 8;
        const bool leftEdge  = (cs == 0);
        const bool rightEdge = (cs + 8 >= BK);
        int cLoff = leftEdge ? 0 : cs - 2;
        // load col window cs-1..cs+8 for the 3 rows (b32 pairs, 1-op unpack)
        float va0[10], va1[10], va2[10];
        {
          unsigned pa = *(const unsigned*)(rp0 + cLoff);
          unsigned w0 = *(const unsigned*)(rp0 + cs);
          unsigned w1 = *(const unsigned*)(rp0 + cs + 2);
          unsigned w2 = *(const unsigned*)(rp0 + cs + 4);
          unsigned w3 = *(const unsigned*)(rp0 + cs + 6);
          unsigned w4 = *(const unsigned*)(rp0 + cs + 8);
          va0[0] = leftEdge ? hL0 : bhi(pa);
          va0[1]=blo(w0); va0[2]=bhi(w0); va0[3]=blo(w1); va0[4]=bhi(w1);
          va0[5]=blo(w2); va0[6]=bhi(w2); va0[7]=blo(w3); va0[8]=bhi(w3);
          va0[9] = rightEdge ? rt0 : blo(w4);
        }
        {
          unsigned pa = *(const unsigned*)(rp1 + cLoff);
          unsigned w0 = *(const unsigned*)(rp1 + cs);
          unsigned w1 = *(const unsigned*)(rp1 + cs + 2);
          unsigned w2 = *(const unsigned*)(rp1 + cs + 4);
          unsigned w3 = *(const unsigned*)(rp1 + cs + 6);
          unsigned w4 = *(const unsigned*)(rp1 + cs + 8);
          va1[0] = leftEdge ? hL1 : bhi(pa);
          va1[1]=blo(w0); va1[2]=bhi(w0); va1[3]=blo(w1); va1[4]=bhi(w1);
          va1[5]=blo(w2); va1[6]=bhi(w2); va1[7]=blo(w3); va1[8]=bhi(w3);
          va1[9] = rightEdge ? rt1 : blo(w4);
        }
        {
          unsigned pa = *(const unsigned*)(rp2 + cLoff);
          unsigned w0 = *(const unsigned*)(rp2 + cs);
          unsigned w1 = *(const unsigned*)(rp2 + cs + 2);
          unsigned w2 = *(const unsigned*)(rp2 + cs + 4);
          unsigned w3 = *(const unsigned*)(rp2 + cs + 6);
          unsigned w4 = *(const unsigned*)(rp2 + cs + 8);
          va2[0] = leftEdge ? hL2 : bhi(pa);
          va2[1]=blo(w0); va2[2]=bhi(w0); va2[3]=blo(w1); va2[4]=bhi(w1);
          va2[5]=blo(w2); va2[6]=bhi(w2); va2[7]=blo(w3); va2[8]=bhi(w3);
          va2[9] = rightEdge ? rt2 : blo(w4);
        }
        #pragma unroll
        for (int c = 0; c < 8; ++c) {
          float cv = wk[0]*va0[c] + wk[1]*va0[c+1] + wk[2]*va0[c+2]
                   + wk[3]*va1[c] + wk[4]*va1[c+1] + wk[5]*va1[c+2]
                   + wk[6]*va2[c] + wk[7]*va2[c+1] + wk[8]*va2[c+2];
          bool vld = rowvalid && ((c0p + cs + c) <= q);
          sv[ch * 8 + c] = vld ? cv : -INFINITY;
          pm = fmaxf(pm, sv[ch * 8 + c]);
        }
      }
      pm = fmaxf(pm, __shfl_xor(pm, 16));
      pm = fmaxf(pm, __shfl_xor(pm, 32));
      const float mn = fmaxf(m_state, pm);
      const float al = __expf(m_state - mn);
      float ps = 0.f;
      short pf16[16];
      #pragma unroll
      for (int c = 0; c < 16; ++c) {
        float p = __expf(sv[c] - mn);
        ps += p;
        pf16[c] = f2bf(p);
      }
      ps += __shfl_xor(ps, 16);
      ps += __shfl_xor(ps, 32);
      m_state = mn;
      l_state = al * l_state + ps;
      if (lg == 0) haloL16[t & 1][r] = rawS16[pb][r][63];
      #pragma unroll
      for (int i = 0; i < 4; ++i) {
        float a = __shfl(al, lg * 4 + i);
        #pragma unroll
        for (int cb = 0; cb < 8; ++cb) oacc[cb][i] *= a;
      }
      bf16x8 pf0, pf1;
      #pragma unroll
      for (int c = 0; c < 8; ++c) { pf0[c] = pf16[c]; pf1[c] = pf16[8 + c]; }
      #pragma unroll
      for (int kk = 0; kk < 2; ++kk) {
        bf16x8 pf = kk ? pf1 : pf0;
        #pragma unroll
        for (int cb = 0; cb < 8; ++cb) {
          int d = cb * 16 + lm;
          int cp = (kk * 4 + lg) ^ (lm & 7);
          bf16x8 vf = *(const bf16x8*)((const char*)&Vt[d][0] + cp * 16);
          oacc[cb] = __builtin_amdgcn_mfma_f32_16x16x32_bf16(pf, vf, oacc[cb], 0, 0, 0);
        }
      }
    }
  }

  // drain outstanding DMA so late LDS writes can't corrupt the next block
  asm volatile("s_waitcnt vmcnt(0)" ::: "memory");

  #pragma unroll
  for (int i = 0; i < 4; ++i) {
    int rr = wid * 16 + lg * 4 + i;
    int q = qr0 + rr;
    float lr = __shfl(l_state, lg * 4 + i);
    if (rr >= 2 && q <= q_cap) {
      float inv = 1.f / lr;
      #pragma unroll
      for (int cb = 0; cb < 8; ++cb) {
        Oh[(size_t)q * DIM + cb * 16 + lm] = oacc[cb][i] * inv;
      }
    }
  }
}

extern "C" void kernel_launch(void* const* d_in, const int* in_sizes, int n_in,
                              void* d_out, int out_size, void* d_ws, size_t ws_size,
                              hipStream_t stream) {
  const float* Q = (const float*)d_in[0];
  const float* K = (const float*)d_in[1];
  const float* V = (const float*)d_in[2];
  const float* W = (const float*)d_in[3];
  float* Out = (float*)d_out;
  short* Kb = (short*)d_ws;                                  // 8 MB
  short* Vw = (short*)((char*)d_ws + (size_t)NHEAD * S_LEN * DIM * 2);  // 8 MB

  prep_k<<<dim3(NHEAD * S_LEN * 16 / 256), 256, 0, stream>>>(K, Kb);
  prep_v<<<dim3(32, NHEAD), 256, 0, stream>>>(V, Vw);

  const int NQT = (S_LEN + BQ - 1) / BQ;   // 34
  dim3 grid(NQT, NHEAD);
  convattn_main<<<grid, 256, 0, stream>>>(Q, Kb, Vw, W, Out);
}

// Round 5
// 104.230 us; speedup vs baseline: 1.8012x; 1.3803x over previous
//
#include <hip/hip_runtime.h>
#include <hip/hip_bf16.h>
#include <math.h>

#define S_LEN 2048
#define DIM   128
#define NHEAD 16
#define BQ    62
#define BK    64
#define SCALE 0.08838834764831845f

typedef __attribute__((ext_vector_type(8))) short bf16x8;
typedef __attribute__((ext_vector_type(4))) float f32x4;
typedef __attribute__((ext_vector_type(2))) float f32x2;

__device__ __forceinline__ short f2bf(float f) {
  union { float f; unsigned u; } v; v.f = f;
  unsigned r = v.u + 0x7fffu + ((v.u >> 16) & 1u);
  return (short)(r >> 16);
}
__device__ __forceinline__ float bhi(unsigned u) {
  union { unsigned v; float f; } x; x.v = u & 0xffff0000u; return x.f;
}
__device__ __forceinline__ float blo(unsigned u) {
  union { unsigned v; float f; } x; x.v = u << 16; return x.f;
}
__device__ __forceinline__ float b2f(short s) {
  union { unsigned v; float f; } x; x.v = ((unsigned)(unsigned short)s) << 16; return x.f;
}
__device__ __forceinline__ unsigned cvtpk(float lo, float hi) {
  unsigned r;
  asm("v_cvt_pk_bf16_f32 %0, %1, %2" : "=v"(r) : "v"(lo), "v"(hi));
  return r;
}
__device__ __forceinline__ f32x2 pkfma(f32x2 a, f32x2 b, f32x2 c) {
  f32x2 d;
  asm("v_pk_fma_f32 %0, %1, %2, %3" : "=v"(d) : "v"(a), "v"(b), "v"(c));
  return d;
}
__device__ __forceinline__ void gll16(const void* gsrc, void* ldst) {
  __builtin_amdgcn_global_load_lds(
      (const __attribute__((address_space(1))) void*)gsrc,
      (__attribute__((address_space(3))) void*)ldst, 16, 0, 0);
}

// ---------- pre-pass 1: K fp32 -> bf16*scale, 16B-chunk XOR-swizzled ----------
__global__ __launch_bounds__(256)
void prep_k(const float* __restrict__ K, short* __restrict__ Kb) {
  int gid = blockIdx.x * 256 + threadIdx.x;
  int chunk = gid & 15;
  int row = gid >> 4;
  int k = row & (S_LEN - 1);
  const float* src = K + (size_t)row * DIM + chunk * 8;
  float4 a = *(const float4*)(src);
  float4 b = *(const float4*)(src + 4);
  bf16x8 o;
  o[0]=f2bf(a.x*SCALE); o[1]=f2bf(a.y*SCALE); o[2]=f2bf(a.z*SCALE); o[3]=f2bf(a.w*SCALE);
  o[4]=f2bf(b.x*SCALE); o[5]=f2bf(b.y*SCALE); o[6]=f2bf(b.z*SCALE); o[7]=f2bf(b.w*SCALE);
  int cp = (chunk & 8) | ((chunk & 7) ^ (k & 7));
  *(bf16x8*)(Kb + (size_t)row * DIM + cp * 8) = o;
}

// ---------- pre-pass 2: V fp32 -> V^T bf16 tiles [h][tile][d][64], swizzled ----------
__global__ __launch_bounds__(256)
void prep_v(const float* __restrict__ V, short* __restrict__ Vw) {
  __shared__ __align__(16) short lv[128][72];
  int tile = blockIdx.x, h = blockIdx.y;
  const float* src = V + ((size_t)h * S_LEN + tile * 64) * DIM;
  int kr = threadIdx.x >> 2, dq = (threadIdx.x & 3) * 32;
  const float* sp = src + (size_t)kr * DIM + dq;
  #pragma unroll
  for (int j = 0; j < 32; j += 4) {
    float4 v = *(const float4*)(sp + j);
    lv[dq + j][kr]     = f2bf(v.x);
    lv[dq + j + 1][kr] = f2bf(v.y);
    lv[dq + j + 2][kr] = f2bf(v.z);
    lv[dq + j + 3][kr] = f2bf(v.w);
  }
  __syncthreads();
  int d = threadIdx.x >> 1, cbase = (threadIdx.x & 1) * 4;
  short* dst = Vw + ((size_t)h * 32 + tile) * 8192 + (size_t)d * 64;
  #pragma unroll
  for (int c0 = 0; c0 < 4; ++c0) {
    int c = cbase + c0;
    bf16x8 val = *(const bf16x8*)&lv[d][c * 8];
    *(bf16x8*)(dst + ((c ^ (d & 7)) * 8)) = val;
  }
}

// ---------- main fused kernel ----------
// Same lag pipeline + counted-vmcnt staging as R3. New: packed-fp32 conv
// (v_pk_fma_f32, both 8-col chunks as .x/.y), cvt_pk_bf16 for P/rawS stores,
// complementary-rank block remap (blocks bx and bx+256 get task sizes summing
// ~const so co-resident workgroups balance).
__global__ __launch_bounds__(256, 2)
void convattn_main(const float* __restrict__ Q, const short* __restrict__ Kb,
                   const short* __restrict__ Vw, const float* __restrict__ W,
                   float* __restrict__ Out) {
  __shared__ __align__(16) short Kt2[2][64][128];
  __shared__ __align__(16) short Vt[128][64];
  __shared__ __align__(16) short rawS16[2][64][66];
  __shared__ short haloL16[2][64];

  const int bx = blockIdx.x;
  const int rank = (bx < 256) ? bx : ((bx < 512) ? (767 - bx) : bx);
  const int qt = 33 - (rank >> 4);
  const int h  = rank & 15;
  const int q0 = qt * BQ;
  const int qr0 = q0 - 2;
  const int q_cap = min(q0 + BQ - 1, S_LEN - 1);
  const int T = q_cap / BK + 1;

  const int tid  = threadIdx.x;
  const int wid  = tid >> 6;
  const int lane = tid & 63;
  const int lm   = lane & 15;
  const int lg   = lane >> 4;

  const float* Qh = Q + (size_t)h * S_LEN * DIM;
  const short* KbH = Kb + (size_t)h * S_LEN * DIM;
  const short* VwH = Vw + (size_t)h * 32 * 8192;
  float* Oh = Out + (size_t)h * S_LEN * DIM;

  f32x2 wp[9];
  #pragma unroll
  for (int i = 0; i < 9; ++i) { float w = W[h * 9 + i]; wp[i][0] = w; wp[i][1] = w; }

  bf16x8 qf[4];
  {
    int qrow = qr0 + wid * 16 + lm;
    int qc = qrow < 0 ? 0 : (qrow >= S_LEN ? S_LEN - 1 : qrow);
    const float* qp = Qh + (size_t)qc * DIM;
    #pragma unroll
    for (int kk = 0; kk < 4; ++kk) {
      int d0 = kk * 32 + lg * 8;
      float4 a = *(const float4*)(qp + d0);
      float4 b = *(const float4*)(qp + d0 + 4);
      bf16x8 f;
      f[0]=f2bf(a.x); f[1]=f2bf(a.y); f[2]=f2bf(a.z); f[3]=f2bf(a.w);
      f[4]=f2bf(b.x); f[5]=f2bf(b.y); f[6]=f2bf(b.z); f[7]=f2bf(b.w);
      qf[kk] = f;
    }
  }
  if (tid < 64) haloL16[0][tid] = 0;

  float m_state = -INFINITY, l_state = 0.f;
  f32x4 oacc[8];
  const f32x4 zero4 = {0.f, 0.f, 0.f, 0.f};
  #pragma unroll
  for (int cb = 0; cb < 8; ++cb) oacc[cb] = zero4;

  __builtin_amdgcn_sched_barrier(0);
  asm volatile("s_waitcnt vmcnt(0)" ::: "memory");
  {
    const char* vg = (const char*)VwH;
    const char* kg = (const char*)KbH;
    char* vl = (char*)&Vt[0][0];
    char* kl = (char*)&Kt2[0][0][0];
    #pragma unroll
    for (int i = 0; i < 4; ++i) {
      int off = wid * 4096 + i * 1024;
      gll16(vg + off + lane * 16, vl + off);
    }
    #pragma unroll
    for (int i = 0; i < 4; ++i) {
      int off = wid * 4096 + i * 1024;
      gll16(kg + off + lane * 16, kl + off);
    }
  }

  for (int t = 0; t <= T; ++t) {
    asm volatile("s_waitcnt lgkmcnt(0)" ::: "memory");
    __builtin_amdgcn_sched_barrier(0);
    __builtin_amdgcn_s_barrier();
    {
      int vsrc = t > 0 ? t - 1 : 0;
      int ksrc = (t + 1 < T) ? t + 1 : T - 1;
      const char* vg = (const char*)(VwH + (size_t)vsrc * 8192);
      const char* kg = (const char*)(KbH + (size_t)ksrc * BK * DIM);
      char* vl = (char*)&Vt[0][0];
      char* kl = (char*)&Kt2[(t + 1) & 1][0][0];
      #pragma unroll
      for (int i = 0; i < 4; ++i) {
        int off = wid * 4096 + i * 1024;
        gll16(vg + off + lane * 16, vl + off);
      }
      #pragma unroll
      for (int i = 0; i < 4; ++i) {
        int off = wid * 4096 + i * 1024;
        gll16(kg + off + lane * 16, kl + off);
      }
    }
    asm volatile("s_waitcnt vmcnt(8)" ::: "memory");
    __builtin_amdgcn_sched_barrier(0);
    __builtin_amdgcn_s_barrier();
    // ---- Phase B: QK^T -> masked bf16 raw tile t ----
    if (t < T) {
      const short(*Ktile)[128] = Kt2[t & 1];
      int k0 = t * BK;
      f32x4 sacc[4];
      #pragma unroll
      for (int cb = 0; cb < 4; ++cb) sacc[cb] = zero4;
      #pragma unroll
      for (int kk = 0; kk < 4; ++kk) {
        #pragma unroll
        for (int cb = 0; cb < 4; ++cb) {
          int c = kk * 4 + lg;
          int cp = (c & 8) | ((c & 7) ^ (lm & 7));
          bf16x8 bf = *(const bf16x8*)((const char*)&Ktile[cb * 16 + lm][0] + cp * 16);
          sacc[cb] = __builtin_amdgcn_mfma_f32_16x16x32_bf16(qf[kk], bf, sacc[cb], 0, 0, 0);
        }
      }
      const int buf = t & 1;
      #pragma unroll
      for (int cb = 0; cb < 4; ++cb) {
        int rr = wid * 16 + lg * 4;
        int cc = cb * 16 + lm;
        #pragma unroll
        for (int i = 0; i < 4; i += 2) {
          float v0 = ((k0 + cc) <= (qr0 + rr + i))     ? sacc[cb][i]     : 0.f;
          float v1 = ((k0 + cc) <= (qr0 + rr + i + 1)) ? sacc[cb][i + 1] : 0.f;
          unsigned pk = cvtpk(v0, v1);
          rawS16[buf][rr + i][cc]     = (short)pk;
          rawS16[buf][rr + i + 1][cc] = (short)(pk >> 16);
        }
      }
    }
    asm volatile("s_waitcnt vmcnt(4) lgkmcnt(0)" ::: "memory");
    __builtin_amdgcn_sched_barrier(0);
    __builtin_amdgcn_s_barrier();
    // ---- Phase C: packed conv + online softmax + PV for tile t-1 ----
    if (t > 0) {
      const int tp = t - 1;
      const int pb = tp & 1, nb = pb ^ 1;
      const int c0p = tp * BK;
      const bool haveRight = (t < T);
      const int r = wid * 16 + lm;
      const int q = qr0 + r;
      const bool rowvalid = (r >= 2) && (q <= q_cap);
      const int a0 = max(r - 2, 0), a1 = max(r - 1, 0);
      const short* rp[3] = { &rawS16[pb][a0][0], &rawS16[pb][a1][0], &rawS16[pb][r][0] };
      const int ridx[3] = { a0, a1, r };
      const int cs0 = lg * 8;          // ch0 cols cs0..cs0+7
      const int cs1 = 32 + lg * 8;     // ch1 cols cs1..cs1+7
      const bool leftEdge  = (lg == 0);
      const bool rightEdge = (lg == 3);
      const int cA = leftEdge ? 0 : cs0 - 2;

      // x[row][d] : d=0..9 <-> cols cs-1..cs+8, .x = ch0, .y = ch1
      f32x2 xv[3][10];
      #pragma unroll
      for (int rw = 0; rw < 3; ++rw) {
        const short* p = rp[rw];
        unsigned a0w = *(const unsigned*)(p + cA);
        unsigned a1w = *(const unsigned*)(p + cs0);
        unsigned a2w = *(const unsigned*)(p + cs0 + 2);
        unsigned a3w = *(const unsigned*)(p + cs0 + 4);
        unsigned a4w = *(const unsigned*)(p + cs0 + 6);
        unsigned a5w = *(const unsigned*)(p + cs0 + 8);
        unsigned b0w = *(const unsigned*)(p + cs1 - 2);
        unsigned b1w = *(const unsigned*)(p + cs1);
        unsigned b2w = *(const unsigned*)(p + cs1 + 2);
        unsigned b3w = *(const unsigned*)(p + cs1 + 4);
        unsigned b4w = *(const unsigned*)(p + cs1 + 6);
        unsigned b5w = *(const unsigned*)(p + cs1 + 8);
        float hv = b2f(haloL16[pb][ridx[rw]]);
        float rv = haveRight ? b2f(rawS16[nb][ridx[rw]][0]) : 0.f;
        xv[rw][0][0] = leftEdge ? hv : bhi(a0w);  xv[rw][0][1] = bhi(b0w);
        xv[rw][1][0] = blo(a1w);  xv[rw][1][1] = blo(b1w);
        xv[rw][2][0] = bhi(a1w);  xv[rw][2][1] = bhi(b1w);
        xv[rw][3][0] = blo(a2w);  xv[rw][3][1] = blo(b2w);
        xv[rw][4][0] = bhi(a2w);  xv[rw][4][1] = bhi(b2w);
        xv[rw][5][0] = blo(a3w);  xv[rw][5][1] = blo(b3w);
        xv[rw][6][0] = bhi(a3w);  xv[rw][6][1] = bhi(b3w);
        xv[rw][7][0] = blo(a4w);  xv[rw][7][1] = blo(b4w);
        xv[rw][8][0] = bhi(a4w);  xv[rw][8][1] = bhi(b4w);
        xv[rw][9][0] = blo(a5w);  xv[rw][9][1] = rightEdge ? rv : blo(b5w);
      }

      const int thr0 = rowvalid ? (q - c0p - cs0) : -1;   // valid iff c <= thr0
      const int thr1 = rowvalid ? (q - c0p - cs1) : -1;
      float svx[8], svy[8];
      float pm = -INFINITY;
      #pragma unroll
      for (int c = 0; c < 8; ++c) {
        f32x2 acc = {0.f, 0.f};
        acc = pkfma(wp[0], xv[0][c],     acc);
        acc = pkfma(wp[1], xv[0][c + 1], acc);
        acc = pkfma(wp[2], xv[0][c + 2], acc);
        acc = pkfma(wp[3], xv[1][c],     acc);
        acc = pkfma(wp[4], xv[1][c + 1], acc);
        acc = pkfma(wp[5], xv[1][c + 2], acc);
        acc = pkfma(wp[6], xv[2][c],     acc);
        acc = pkfma(wp[7], xv[2][c + 1], acc);
        acc = pkfma(wp[8], xv[2][c + 2], acc);
        svx[c] = (c <= thr0) ? acc[0] : -INFINITY;
        svy[c] = (c <= thr1) ? acc[1] : -INFINITY;
        pm = fmaxf(pm, fmaxf(svx[c], svy[c]));
      }
      pm = fmaxf(pm, __shfl_xor(pm, 16));
      pm = fmaxf(pm, __shfl_xor(pm, 32));
      const float mn = fmaxf(m_state, pm);
      const float al = __expf(m_state - mn);
      float ps = 0.f;
      union { bf16x8 v; unsigned u[4]; } pf0u, pf1u;
      #pragma unroll
      for (int c = 0; c < 8; c += 2) {
        float p0 = __expf(svx[c] - mn);
        float p1 = __expf(svx[c + 1] - mn);
        float p2 = __expf(svy[c] - mn);
        float p3 = __expf(svy[c + 1] - mn);
        ps += (p0 + p1) + (p2 + p3);
        pf0u.u[c >> 1] = cvtpk(p0, p1);
        pf1u.u[c >> 1] = cvtpk(p2, p3);
      }
      ps += __shfl_xor(ps, 16);
      ps += __shfl_xor(ps, 32);
      m_state = mn;
      l_state = al * l_state + ps;
      if (lg == 0) haloL16[t & 1][r] = rawS16[pb][r][63];
      #pragma unroll
      for (int i = 0; i < 4; ++i) {
        float a = __shfl(al, lg * 4 + i);
        #pragma unroll
        for (int cb = 0; cb < 8; ++cb) oacc[cb][i] *= a;
      }
      #pragma unroll
      for (int kk = 0; kk < 2; ++kk) {
        bf16x8 pf = kk ? pf1u.v : pf0u.v;
        #pragma unroll
        for (int cb = 0; cb < 8; ++cb) {
          int d = cb * 16 + lm;
          int cp = (kk * 4 + lg) ^ (lm & 7);
          bf16x8 vf = *(const bf16x8*)((const char*)&Vt[d][0] + cp * 16);
          oacc[cb] = __builtin_amdgcn_mfma_f32_16x16x32_bf16(pf, vf, oacc[cb], 0, 0, 0);
        }
      }
    }
  }

  asm volatile("s_waitcnt vmcnt(0)" ::: "memory");

  #pragma unroll
  for (int i = 0; i < 4; ++i) {
    int rr = wid * 16 + lg * 4 + i;
    int q = qr0 + rr;
    float lr = __shfl(l_state, lg * 4 + i);
    if (rr >= 2 && q <= q_cap) {
      float inv = 1.f / lr;
      #pragma unroll
      for (int cb = 0; cb < 8; ++cb) {
        Oh[(size_t)q * DIM + cb * 16 + lm] = oacc[cb][i] * inv;
      }
    }
  }
}

extern "C" void kernel_launch(void* const* d_in, const int* in_sizes, int n_in,
                              void* d_out, int out_size, void* d_ws, size_t ws_size,
                              hipStream_t stream) {
  const float* Q = (const float*)d_in[0];
  const float* K = (const float*)d_in[1];
  const float* V = (const float*)d_in[2];
  const float* W = (const float*)d_in[3];
  float* Out = (float*)d_out;
  short* Kb = (short*)d_ws;
  short* Vw = (short*)((char*)d_ws + (size_t)NHEAD * S_LEN * DIM * 2);

  prep_k<<<dim3(NHEAD * S_LEN * 16 / 256), 256, 0, stream>>>(K, Kb);
  prep_v<<<dim3(32, NHEAD), 256, 0, stream>>>(V, Vw);

  convattn_main<<<dim3(544), 256, 0, stream>>>(Q, Kb, Vw, W, Out);
}